// Round 13
// baseline (1229.659 us; speedup 1.0000x reference)
//
#include <hip/hip_runtime.h>
#include <math.h>

// Problem constants
#define BB 16
#define NN 8192
#define SS 1024
#define GG 32
#define MTOT (BB*SS*GG)   // 524288
// MLP: 6 -> 64 -> 64 -> 128

struct alignas(16) f4 { float v[4]; };

typedef __attribute__((ext_vector_type(8))) short bfrag;   // 8 bf16 = 4 VGPR
typedef __attribute__((ext_vector_type(4))) float facc;    // 4 f32 acc

#define MFMA16(a, b, c) __builtin_amdgcn_mfma_f32_16x16x32_bf16(a, b, c, 0, 0, 0)

__device__ __forceinline__ unsigned short f2bf(float f) {
    const unsigned u = __float_as_uint(f);
    return (unsigned short)((u + 0x7FFFu + ((u >> 16) & 1u)) >> 16);
}
__device__ __forceinline__ unsigned packbf(float lo, float hi) {
    return (unsigned)f2bf(lo) | ((unsigned)f2bf(hi) << 16);
}

template<int CTRL>
__device__ __forceinline__ int dppmov(int x) {
    return __builtin_amdgcn_update_dpp(x, x, CTRL, 0xF, 0xF, true);
}
// one u64 max-reduce level via DPP permutation of (hi,lo)
template<int CTRL>
__device__ __forceinline__ void dlevel(int& hi, int& lo) {
    const int oh = dppmov<CTRL>(hi);
    const int ol = dppmov<CTRL>(lo);
    const unsigned long long o =
        ((unsigned long long)(unsigned)oh << 32) | (unsigned)ol;
    const unsigned long long c =
        ((unsigned long long)(unsigned)hi << 32) | (unsigned)lo;
    if (o > c) { hi = oh; lo = ol; }
}
// 16-lane-group sum via ROW_ROR rotate-reduce (every lane gets group total)
__device__ __forceinline__ float dppadd16(float x) {
    x += __int_as_float(dppmov<0x121>(__float_as_int(x)));   // ROW_ROR:1
    x += __int_as_float(dppmov<0x122>(__float_as_int(x)));   // ROW_ROR:2
    x += __int_as_float(dppmov<0x124>(__float_as_int(x)));   // ROW_ROR:4
    x += __int_as_float(dppmov<0x128>(__float_as_int(x)));   // ROW_ROR:8
    return x;
}

// ---------------------------------------------------------------------------
// FPS. Scalar __f*_rn distance math ONLY (packed-f32 failed twice with
// identical wrong output — dead end, do not revisit).
// Round-13 changes: (a) NO global stores in the step loop — centroids go to
// a 12KB LDS buffer, one cooperative f4 copy at the end => the per-step
// __syncthreads no longer drains vmcnt (the loop has zero vmem ops).
// (b) Wave winners publish (key, x, y, z): lane 0 resolves its winner's
// coords from LDS BEFORE the barrier; post-barrier all threads select the
// max of 4 keys + cndmask the coords — removes the serial scan->lx[far]
// two-phase, and the 'far' index entirely. WAR safety: parity double-buffer,
// slot[s&1] overwritten at s+2, after s+1's barrier => all step-s reads done.
// ---------------------------------------------------------------------------
__global__ __launch_bounds__(256) void fps_kernel(const float* __restrict__ xyz,
                                                  float* __restrict__ newxyz)
{
    __shared__ float lx[NN], ly[NN], lz[NN];            // 96 KB
    __shared__ unsigned long long skey[2][4];
    __shared__ float sxw[2][4], syw[2][4], szw[2][4];
    __shared__ alignas(16) float outLds[SS * 3];        // 12 KB
    const int b = blockIdx.x;
    const int t = threadIdx.x;
    const int wave = t >> 6, lane = t & 63;
    const float* base = xyz + (size_t)b * NN * 3;

    float px[32], py[32], pz[32], dd[32];
#pragma unroll
    for (int k = 0; k < 32; ++k) {
        const int p = (k << 8) + t;
        const float x = base[p * 3 + 0];
        const float y = base[p * 3 + 1];
        const float z = base[p * 3 + 2];
        px[k] = x; py[k] = y; pz[k] = z; dd[k] = 1e10f;
        lx[p] = x; ly[p] = y; lz[p] = z;
    }
    __syncthreads();

    float cx = lx[0], cy = ly[0], cz = lz[0];
    for (int s = 0; s < SS; ++s) {
        if (t == 0) {
            outLds[s * 3 + 0] = cx;
            outLds[s * 3 + 1] = cy;
            outLds[s * 3 + 2] = cz;
        }
        float bf = -1.f;
        unsigned binv = 0u;
#pragma unroll
        for (int k = 0; k < 32; ++k) {
            const float dx = __fsub_rn(px[k], cx);
            const float dy = __fsub_rn(py[k], cy);
            const float dz = __fsub_rn(pz[k], cz);
            const float d  = __fadd_rn(__fadd_rn(__fmul_rn(dx, dx), __fmul_rn(dy, dy)),
                                       __fmul_rn(dz, dz));
            const float nd = fminf(dd[k], d);
            dd[k] = nd;
            if (nd > bf) {                         // strict > keeps lowest k
                bf = nd;
                binv = 0xFFFFFFFFu - (unsigned)((k << 8) + t);
            }
        }

        int hi = __float_as_int(bf);   // bf >= 0 -> monotone bit pattern
        int lo = (int)binv;
        dlevel<0x121>(hi, lo);         // ROW_ROR:1
        dlevel<0x122>(hi, lo);         // ROW_ROR:2
        dlevel<0x124>(hi, lo);         // ROW_ROR:4
        dlevel<0x128>(hi, lo);         // ROW_ROR:8  -> max over each 16-row
        {
            const int oh = __shfl_xor(hi, 16), ol = __shfl_xor(lo, 16);
            const unsigned long long o =
                ((unsigned long long)(unsigned)oh << 32) | (unsigned)ol;
            const unsigned long long c =
                ((unsigned long long)(unsigned)hi << 32) | (unsigned)lo;
            if (o > c) { hi = oh; lo = ol; }
        }
        {
            const int oh = __shfl_xor(hi, 32), ol = __shfl_xor(lo, 32);
            const unsigned long long o =
                ((unsigned long long)(unsigned)oh << 32) | (unsigned)ol;
            const unsigned long long c =
                ((unsigned long long)(unsigned)hi << 32) | (unsigned)lo;
            if (o > c) { hi = oh; lo = ol; }
        }

        if (lane == 0) {
            const int wi = (int)(0xFFFFFFFFu - (unsigned)lo);
            skey[s & 1][wave] =
                ((unsigned long long)(unsigned)hi << 32) | (unsigned)lo;
            sxw[s & 1][wave] = lx[wi];
            syw[s & 1][wave] = ly[wi];
            szw[s & 1][wave] = lz[wi];
        }
        __syncthreads();
        const unsigned long long k0 = skey[s & 1][0], k1 = skey[s & 1][1];
        const unsigned long long k2 = skey[s & 1][2], k3 = skey[s & 1][3];
        const float x0 = sxw[s & 1][0], x1 = sxw[s & 1][1], x2 = sxw[s & 1][2], x3 = sxw[s & 1][3];
        const float y0 = syw[s & 1][0], y1 = syw[s & 1][1], y2 = syw[s & 1][2], y3 = syw[s & 1][3];
        const float z0 = szw[s & 1][0], z1 = szw[s & 1][1], z2 = szw[s & 1][2], z3 = szw[s & 1][3];
        const bool c01 = (k1 > k0);
        const unsigned long long ka = c01 ? k1 : k0;
        const float xa = c01 ? x1 : x0, ya = c01 ? y1 : y0, za = c01 ? z1 : z0;
        const bool c23 = (k3 > k2);
        const unsigned long long kb = c23 ? k3 : k2;
        const float xb2 = c23 ? x3 : x2, yb2 = c23 ? y3 : y2, zb2 = c23 ? z3 : z2;
        const bool cab = (kb > ka);
        cx = cab ? xb2 : xa;
        cy = cab ? yb2 : ya;
        cz = cab ? zb2 : za;
    }

    __syncthreads();
    // cooperative copy of centroids to global (the only vmem after staging)
    {
        const f4* src = (const f4*)outLds;              // 768 f4
        f4* dst = (f4*)(newxyz + (size_t)b * SS * 3);
#pragma unroll
        for (int i = 0; i < 3; ++i)
            dst[i * 256 + t] = src[i * 256 + t];
    }
}

// ---------------------------------------------------------------------------
// ball query + gather + v moments (round-12 verbatim: 2-chunk unrolled scan).
// ---------------------------------------------------------------------------
__global__ __launch_bounds__(256) void ball_gather_kernel(const float* __restrict__ xyz,
                                                          const float* __restrict__ feat,
                                                          const float* __restrict__ newxyz,
                                                          float* __restrict__ v,
                                                          float* __restrict__ part1)
{
    const int wid  = (int)((blockIdx.x * 256 + threadIdx.x) >> 6);
    const int lane = threadIdx.x & 63;
    if (wid >= BB * SS) return;
    const int b = wid >> 10;

    const float cx = newxyz[wid * 3 + 0];
    const float cy = newxyz[wid * 3 + 1];
    const float cz = newxyz[wid * 3 + 2];
    const float* xb = xyz + (size_t)b * NN * 3;
    const float* fb = feat + (size_t)b * NN * 3;
    const size_t mbase = (size_t)wid * GG;

    float mS[6];
    float mP[36];
#pragma unroll
    for (int c = 0; c < 6; ++c) mS[c] = 0.f;
#pragma unroll
    for (int c = 0; c < 36; ++c) mP[c] = 0.f;

    int cnt = 0, firstp = -1;

    auto emit = [&](int p, float x, float y, float z, int pos) {
        const size_t mm = mbase + pos;
        float a[6];
        a[0] = __fsub_rn(x, cx);
        a[1] = __fsub_rn(y, cy);
        a[2] = __fsub_rn(z, cz);
        a[3] = fb[p * 3 + 0];
        a[4] = fb[p * 3 + 1];
        a[5] = fb[p * 3 + 2];
#pragma unroll
        for (int c = 0; c < 6; ++c) {
            v[(size_t)c * MTOT + mm] = a[c];
            mS[c] += a[c];
#pragma unroll
            for (int dch = 0; dch < 6; ++dch)
                mP[c * 6 + dch] = fmaf(a[c], a[dch], mP[c * 6 + dch]);
        }
    };

    for (int base = 0; base < NN && cnt < GG; base += 128) {
        const int pA = base + lane;
        const int pB = base + 64 + lane;
        const float xA = xb[pA * 3 + 0], yA = xb[pA * 3 + 1], zA = xb[pA * 3 + 2];
        const float xB = xb[pB * 3 + 0], yB = xb[pB * 3 + 1], zB = xb[pB * 3 + 2];

        const float dxA = __fsub_rn(cx, xA), dyA = __fsub_rn(cy, yA), dzA = __fsub_rn(cz, zA);
        const float dA  = __fadd_rn(__fadd_rn(__fmul_rn(dxA, dxA), __fmul_rn(dyA, dyA)),
                                    __fmul_rn(dzA, dzA));
        const float dxB = __fsub_rn(cx, xB), dyB = __fsub_rn(cy, yB), dzB = __fsub_rn(cz, zB);
        const float dB  = __fadd_rn(__fadd_rn(__fmul_rn(dxB, dxB), __fmul_rn(dyB, dyB)),
                                    __fmul_rn(dzB, dzB));

        const bool hitA = (dA <= 0.04f);
        const bool hitB = (dB <= 0.04f);
        const unsigned long long mA = __ballot(hitA);
        const unsigned long long mB = __ballot(hitB);

        if (firstp < 0) {
            if (mA != 0ull)      firstp = base + (int)__builtin_ctzll(mA);
            else if (mB != 0ull) firstp = base + 64 + (int)__builtin_ctzll(mB);
        }

        const int posA = cnt + (int)__popcll(mA & ((1ull << lane) - 1ull));
        if (hitA && posA < GG) emit(pA, xA, yA, zA, posA);
        const int cntA = cnt + (int)__popcll(mA);

        const int posB = cntA + (int)__popcll(mB & ((1ull << lane) - 1ull));
        if (hitB && posB < GG) emit(pB, xB, yB, zB, posB);
        cnt = cntA + (int)__popcll(mB);
    }
    if (cnt < GG) {
        const int p = firstp;
        const float x = xb[p * 3 + 0], y = xb[p * 3 + 1], z = xb[p * 3 + 2];
        float a[6];
        a[0] = __fsub_rn(x, cx);
        a[1] = __fsub_rn(y, cy);
        a[2] = __fsub_rn(z, cz);
        a[3] = fb[p * 3 + 0];
        a[4] = fb[p * 3 + 1];
        a[5] = fb[p * 3 + 2];
        for (int j = cnt + lane; j < GG; j += 64) {
            const size_t mm = mbase + j;
#pragma unroll
            for (int c = 0; c < 6; ++c) {
                v[(size_t)c * MTOT + mm] = a[c];
                mS[c] += a[c];
#pragma unroll
                for (int dch = 0; dch < 6; ++dch)
                    mP[c * 6 + dch] = fmaf(a[c], a[dch], mP[c * 6 + dch]);
            }
        }
    }
#pragma unroll
    for (int off = 1; off < 64; off <<= 1) {
#pragma unroll
        for (int c = 0; c < 6; ++c) mS[c] += __shfl_xor(mS[c], off);
#pragma unroll
        for (int c = 0; c < 36; ++c) mP[c] += __shfl_xor(mP[c], off);
    }
    if (lane == 0) {
        float* row = part1 + (size_t)wid * 42;
#pragma unroll
        for (int c = 0; c < 6; ++c) row[c] = mS[c];
#pragma unroll
        for (int c = 0; c < 36; ++c) row[6 + c] = mP[c];
    }
}

// ---------------------------------------------------------------------------
// reduce1: collapse part1 (16384 x 42) -> red64 (64 x 42). 64 blocks x 256.
// ---------------------------------------------------------------------------
__global__ __launch_bounds__(256) void reduce1_kernel(const float* __restrict__ part1,
                                                      float* __restrict__ red64)
{
    __shared__ float ldsT[42][260];
    const int tid = threadIdx.x;
    const int row = (int)blockIdx.x * 256 + tid;
    const float* rp = part1 + (size_t)row * 42;
    float r42[42];
#pragma unroll
    for (int i = 0; i < 21; ++i) {
        const float2 v2 = *reinterpret_cast<const float2*>(rp + 2 * i);
        r42[2 * i] = v2.x; r42[2 * i + 1] = v2.y;
    }
#pragma unroll
    for (int c = 0; c < 42; ++c) ldsT[c][tid] = r42[c];
    __syncthreads();
    if (tid < 168) {
        const int c = tid >> 2, r = tid & 3;
        float s = 0.f;
#pragma unroll
        for (int k = 0; k < 64; ++k) s += ldsT[c][r * 64 + k];
        ldsT[c][256 + r] = s;   // pad columns 256..259
    }
    __syncthreads();
    if (tid < 42)
        red64[(size_t)blockIdx.x * 42 + tid] =
            (ldsT[tid][256] + ldsT[tid][257]) + (ldsT[tid][258] + ldsT[tid][259]);
}

// ---------------------------------------------------------------------------
// finalize1 (+prep merged, 1024 thr): build raw bf16 W2/W3 A-frags; reduce
// red64 (64 x 42); analytic BN1; emit folded W1 frags + c1.
// ---------------------------------------------------------------------------
__global__ __launch_bounds__(1024) void finalize1_kernel(const float* __restrict__ red64,
                                                         const float* __restrict__ w0,
                                                         const float* __restrict__ g0,
                                                         const float* __restrict__ bt0,
                                                         const float* __restrict__ w1g,
                                                         const float* __restrict__ w2g,
                                                         short* __restrict__ wf1,
                                                         float* __restrict__ c1,
                                                         short* __restrict__ wf2r,
                                                         short* __restrict__ wf3r)
{
    const int tid = threadIdx.x;
    if (tid < 512) {
        const int f = tid >> 6, l = tid & 63;
        const int o = (f >> 1) * 16 + (l & 15);
        const int kb = (f & 1) * 32 + (l >> 4) * 8;
#pragma unroll
        for (int j = 0; j < 8; ++j)
            wf2r[tid * 8 + j] = (short)f2bf(w1g[o * 64 + kb + j]);
    }
    {
        const int f = tid >> 6, l = tid & 63;
        const int o = (f >> 1) * 16 + (l & 15);
        const int kb = (f & 1) * 32 + (l >> 4) * 8;
#pragma unroll
        for (int j = 0; j < 8; ++j)
            wf3r[tid * 8 + j] = (short)f2bf(w2g[o * 64 + kb + j]);
    }

    __shared__ double red[672];
    __shared__ double tot[42];
    __shared__ float Asf[64];
    if (tid < 672) {
        const int j = tid % 42, r = tid / 42;   // 16 reducers per moment
        double s = 0.0;
#pragma unroll
        for (int i = r; i < 64; i += 16) s += (double)red64[(size_t)i * 42 + j];
        red[tid] = s;
    }
    __syncthreads();
    if (tid < 42) {
        double s = 0.0;
        for (int r = 0; r < 16; ++r) s += red[r * 42 + tid];
        tot[tid] = s / (double)MTOT;
    }
    __syncthreads();
    if (tid < 64) {
        double m1 = 0.0;
        for (int c = 0; c < 6; ++c) m1 += (double)w0[tid * 6 + c] * tot[c];
        double e2 = 0.0;
        for (int c = 0; c < 6; ++c)
            for (int d = 0; d < 6; ++d)
                e2 += (double)w0[tid * 6 + c] * (double)w0[tid * 6 + d] * tot[6 + c * 6 + d];
        double var = e2 - m1 * m1;
        if (var < 0.0) var = 0.0;
        const double A = (double)g0[tid] / sqrt(var + 1e-5);
        Asf[tid] = (float)A;
        c1[tid] = (float)((double)bt0[tid] - A * m1);
    }
    __syncthreads();
    if (tid < 256) {
        const int l = tid & 63;
        const int o = (tid >> 6) * 16 + (l & 15);
        const int h = l >> 4;
#pragma unroll
        for (int j = 0; j < 8; ++j) {
            const float val = (h == 0 && j < 6) ? Asf[o] * w0[o * 6 + j] : 0.f;
            wf1[tid * 8 + j] = (short)f2bf(val);
        }
    }
}

// ---------------------------------------------------------------------------
// MFMA chain kernel (round-11/12 verbatim: DPP rotate-add stats reduce).
// PHASE 2: stats of x2_nb. PHASE 3: stats of x3_nb + pre-BN3 group max.
// ---------------------------------------------------------------------------
template<int PHASE>
__global__ __launch_bounds__(256, 2) void chain_kernel(
    const float* __restrict__ v,
    const short* __restrict__ wf1, const float* __restrict__ c1,
    const short* __restrict__ wf2, const float* __restrict__ c2,
    const short* __restrict__ wf3,
    float* __restrict__ part, float* __restrict__ gmax, int tpb)
{
    __shared__ alignas(16) unsigned Hu1[4][16][36];
    __shared__ alignas(16) unsigned Hu2[(PHASE == 3) ? 4 : 1][16][36];
    __shared__ alignas(16) short w3l[(PHASE == 3) ? 8192 : 8];
    __shared__ alignas(16) float gm[(PHASE == 3) ? 4 : 1][128][20];
    __shared__ float redf[4][4][64];

    const int tid = threadIdx.x;
    const int w = tid >> 6, l = tid & 63;
    const int mcol = l & 15, h = l >> 4;

    if constexpr (PHASE == 3) {
        const unsigned* src = (const unsigned*)wf3;
        unsigned* dst = (unsigned*)w3l;
        for (int i = tid; i < 4096; i += 256) dst[i] = src[i];
    }
    __syncthreads();

    bfrag a1[4];
#pragma unroll
    for (int t = 0; t < 4; ++t) a1[t] = *(const bfrag*)&wf1[(t * 64 + l) * 8];
    bfrag a2[8];
#pragma unroll
    for (int f = 0; f < 8; ++f) a2[f] = *(const bfrag*)&wf2[(f * 64 + l) * 8];
    float c1v[16];
#pragma unroll
    for (int t = 0; t < 4; ++t)
#pragma unroll
        for (int r = 0; r < 4; ++r) c1v[t * 4 + r] = c1[t * 16 + h * 4 + r];
    float c2v[16];
    if constexpr (PHASE == 3) {
#pragma unroll
        for (int t = 0; t < 4; ++t)
#pragma unroll
            for (int r = 0; r < 4; ++r) c2v[t * 4 + r] = c2[t * 16 + h * 4 + r];
    }

    constexpr int NS = (PHASE == 3) ? 32 : 16;
    float sA[NS], qA[NS];
#pragma unroll
    for (int i = 0; i < NS; ++i) { sA[i] = 0.f; qA[i] = 0.f; }

    const facc zf = {0.f, 0.f, 0.f, 0.f};

    for (int ti = 0; ti < tpb; ++ti) {
        const int tile = blockIdx.x * tpb + ti;
        float mx[(PHASE == 3) ? 32 : 1];
        if constexpr (PHASE == 3) {
#pragma unroll
            for (int i = 0; i < 32; ++i) mx[i] = -3.0e38f;
        }

#pragma unroll
        for (int st = 0; st < 2; ++st) {
            const int mg = tile * 128 + w * 32 + st * 16 + mcol;

            bfrag bv;
#pragma unroll
            for (int j = 0; j < 8; ++j) bv[j] = 0;
            if (h == 0) {
#pragma unroll
                for (int j = 0; j < 6; ++j)
                    bv[j] = (short)f2bf(v[(size_t)j * MTOT + mg]);
            }
            facc x1[4];
#pragma unroll
            for (int t = 0; t < 4; ++t) x1[t] = MFMA16(a1[t], bv, zf);
#pragma unroll
            for (int t = 0; t < 4; ++t)
#pragma unroll
                for (int rr = 0; rr < 2; ++rr)
                    Hu1[w][mcol][t * 8 + h * 2 + rr] = packbf(
                        fmaxf(x1[t][2 * rr]     + c1v[t * 4 + 2 * rr],     0.f),
                        fmaxf(x1[t][2 * rr + 1] + c1v[t * 4 + 2 * rr + 1], 0.f));

            const bfrag b0 = *(const bfrag*)&Hu1[w][mcol][h * 4];
            const bfrag b1 = *(const bfrag*)&Hu1[w][mcol][16 + h * 4];

            if constexpr (PHASE == 2) {
#pragma unroll
                for (int t = 0; t < 4; ++t) {
                    facc a = MFMA16(a2[2 * t], b0, zf);
                    a = MFMA16(a2[2 * t + 1], b1, a);
#pragma unroll
                    for (int r = 0; r < 4; ++r) {
                        const float x = a[r];
                        sA[t * 4 + r] += x;
                        qA[t * 4 + r] = fmaf(x, x, qA[t * 4 + r]);
                    }
                }
            } else {
#pragma unroll
                for (int t = 0; t < 4; ++t) {
                    facc a = MFMA16(a2[2 * t], b0, zf);
                    a = MFMA16(a2[2 * t + 1], b1, a);
#pragma unroll
                    for (int rr = 0; rr < 2; ++rr)
                        Hu2[w][mcol][t * 8 + h * 2 + rr] = packbf(
                            fmaxf(a[2 * rr]     + c2v[t * 4 + 2 * rr],     0.f),
                            fmaxf(a[2 * rr + 1] + c2v[t * 4 + 2 * rr + 1], 0.f));
                }
                const bfrag d0 = *(const bfrag*)&Hu2[w][mcol][h * 4];
                const bfrag d1 = *(const bfrag*)&Hu2[w][mcol][16 + h * 4];
#pragma unroll
                for (int t3 = 0; t3 < 8; ++t3) {
                    const bfrag wa = *(const bfrag*)&w3l[((t3 * 2 + 0) * 64 + l) * 8];
                    const bfrag wb = *(const bfrag*)&w3l[((t3 * 2 + 1) * 64 + l) * 8];
                    facc a = MFMA16(wa, d0, zf);
                    a = MFMA16(wb, d1, a);
#pragma unroll
                    for (int r = 0; r < 4; ++r) {
                        const float x = a[r];
                        const int i = t3 * 4 + r;
                        sA[i] += x;
                        qA[i] = fmaf(x, x, qA[i]);
                        mx[i] = fmaxf(mx[i], x);
                    }
                }
            }
        }

        if constexpr (PHASE == 3) {
#pragma unroll
            for (int t3 = 0; t3 < 8; ++t3)
#pragma unroll
                for (int r = 0; r < 4; ++r)
                    gm[w][t3 * 16 + h * 4 + r][mcol] = mx[t3 * 4 + r];
            float m0 = -3.0e38f, m1 = -3.0e38f;
#pragma unroll
            for (int c4i = 0; c4i < 4; ++c4i) {
                const facc v0 = *(const facc*)&gm[w][2 * l][c4i * 4];
                const facc v1 = *(const facc*)&gm[w][2 * l + 1][c4i * 4];
#pragma unroll
                for (int jj = 0; jj < 4; ++jj) {
                    m0 = fmaxf(m0, v0[jj]);
                    m1 = fmaxf(m1, v1[jj]);
                }
            }
            const int g = tile * 4 + w;
            gmax[(size_t)g * 128 + 2 * l]     = m0;
            gmax[(size_t)g * 128 + 2 * l + 1] = m1;
        }
    }

    // 16-lane-group stats reduce via DPP rotate-add (VALU pipe)
#pragma unroll
    for (int i = 0; i < NS; ++i) {
        sA[i] = dppadd16(sA[i]);
        qA[i] = dppadd16(qA[i]);
    }
    __syncthreads();
    if (mcol == 0) {
#pragma unroll
        for (int i = 0; i < NS; ++i) {
            redf[w][h][i] = sA[i];
            redf[w][h][NS + i] = qA[i];
        }
    }
    __syncthreads();
    if constexpr (PHASE == 2) {
        if (tid < 128) {
            const int o = tid & 63, sq = tid >> 6;
            const int i = (o >> 4) * 4 + (o & 3), hh = (o >> 2) & 3;
            const int idx = sq * 16 + i;
            const float s = redf[0][hh][idx] + redf[1][hh][idx] +
                            redf[2][hh][idx] + redf[3][hh][idx];
            part[(size_t)blockIdx.x * 128 + sq * 64 + o] = s;
        }
    } else {
        if (tid < 256) {
            const int o = tid & 127, sq = tid >> 7;
            const int i = (o >> 4) * 4 + (o & 3), hh = (o >> 2) & 3;
            const int idx = sq * 32 + i;
            const float s = redf[0][hh][idx] + redf[1][hh][idx] +
                            redf[2][hh][idx] + redf[3][hh][idx];
            part[(size_t)blockIdx.x * 256 + sq * 128 + o] = s;
        }
    }
}

// ---------------------------------------------------------------------------
// finalize2 (1024 thr, 8 reducers/stat, unroll-4): chain<2> partials
// (2048 x [s64|q64]) -> A2/c2; emit folded bf16 W2 A-frags.
// ---------------------------------------------------------------------------
__global__ __launch_bounds__(1024) void finalize2_kernel(const float* __restrict__ part,
                                                         const float* __restrict__ w1g,
                                                         const float* __restrict__ g1,
                                                         const float* __restrict__ bt1,
                                                         short* __restrict__ wf2f,
                                                         float* __restrict__ c2)
{
    __shared__ double tot[1024];
    __shared__ float As[64];
    const int tid = threadIdx.x;
    const int j = tid & 127, r = tid >> 7;    // 8 reducers per stat
    double s = 0.0;
#pragma unroll 4
    for (int blk = r; blk < 2048; blk += 8) s += (double)part[(size_t)blk * 128 + j];
    tot[tid] = s;
    __syncthreads();
    if (tid < 128) {
        double t = 0.0;
#pragma unroll
        for (int g = 0; g < 8; ++g) t += tot[g * 128 + tid];
        tot[tid] = t;
    }
    __syncthreads();
    if (tid < 64) {
        const double mean = tot[tid] / (double)MTOT;
        double var = tot[64 + tid] / (double)MTOT - mean * mean;
        if (var < 0.0) var = 0.0;
        const double A = (double)g1[tid] / sqrt(var + 1e-5);
        As[tid] = (float)A;
        c2[tid] = (float)((double)bt1[tid] - A * mean);
    }
    __syncthreads();
    if (tid < 512) {
        const int f = tid >> 6, l = tid & 63;
        const int o = (f >> 1) * 16 + (l & 15);
        const int kb = (f & 1) * 32 + (l >> 4) * 8;
#pragma unroll
        for (int j8 = 0; j8 < 8; ++j8)
            wf2f[tid * 8 + j8] = (short)f2bf(As[o] * w1g[o * 64 + kb + j8]);
    }
}

// ---------------------------------------------------------------------------
// finalize3 (1024 thr, 4 reducers/stat, unroll-4): chain<3> partials
// (2048 x [s128|q128]) -> A3/c3.
// ---------------------------------------------------------------------------
__global__ __launch_bounds__(1024) void finalize3_kernel(const float* __restrict__ part,
                                                         const float* __restrict__ g2,
                                                         const float* __restrict__ bt2,
                                                         float* __restrict__ A3,
                                                         float* __restrict__ c3)
{
    __shared__ double tot[1024];
    const int tid = threadIdx.x;
    const int j = tid & 255, r = tid >> 8;    // 2 reducers per stat
    double s = 0.0;
#pragma unroll 4
    for (int blk = r; blk < 2048; blk += 4) s += (double)part[(size_t)blk * 256 + j];
    tot[tid] = s;
    __syncthreads();
    if (tid < 256) {
        const double t = tot[tid] + tot[256 + tid] + tot[512 + tid] + tot[768 + tid];
        tot[tid] = t;
    }
    __syncthreads();
    if (tid < 128) {
        const double mean = tot[tid] / (double)MTOT;
        double var = tot[128 + tid] / (double)MTOT - mean * mean;
        if (var < 0.0) var = 0.0;
        const double A = (double)g2[tid] / sqrt(var + 1e-5);
        A3[tid] = (float)A;
        c3[tid] = (float)((double)bt2[tid] - A * mean);
    }
}

// ---------------------------------------------------------------------------
// final_out: in-place out = relu(A3*gmax + c3) over (16384 groups x 128 ch).
// ---------------------------------------------------------------------------
__global__ __launch_bounds__(256) void final_out_kernel(float* __restrict__ outF,
                                                        const float* __restrict__ A3,
                                                        const float* __restrict__ c3)
{
    __shared__ float As[128], Cs[128];
    const int tid = threadIdx.x;
    if (tid < 128) { As[tid] = A3[tid]; Cs[tid] = c3[tid]; }
    __syncthreads();
    const int idx = (int)blockIdx.x * 256 + tid;      // f4 index, total 524288
    f4 val = *reinterpret_cast<f4*>(&outF[(size_t)idx * 4]);
    const int chb = (idx * 4) & 127;
#pragma unroll
    for (int jj = 0; jj < 4; ++jj)
        val.v[jj] = fmaxf(fmaf(As[chb + jj], val.v[jj], Cs[chb + jj]), 0.f);
    *reinterpret_cast<f4*>(&outF[(size_t)idx * 4]) = val;
}

// ---------------------------------------------------------------------------
extern "C" void kernel_launch(void* const* d_in, const int* in_sizes, int n_in,
                              void* d_out, int out_size, void* d_ws, size_t ws_size,
                              hipStream_t stream)
{
    const float* xyz  = (const float*)d_in[0];
    const float* feat = (const float*)d_in[1];
    const float* w0  = (const float*)d_in[2];
    const float* g0  = (const float*)d_in[4];
    const float* bt0 = (const float*)d_in[5];
    const float* w1  = (const float*)d_in[6];
    const float* g1  = (const float*)d_in[8];
    const float* bt1 = (const float*)d_in[9];
    const float* w2  = (const float*)d_in[10];
    const float* g2  = (const float*)d_in[12];
    const float* bt2 = (const float*)d_in[13];

    float* out    = (float*)d_out;
    float* newxyz = out;                 // (16,1024,3)
    float* outF   = out + BB * SS * 3;   // (16,1024,128) — gmax then final

    float* wsf   = (float*)d_ws;
    float* v     = wsf;                        // 3145728 floats
    float* part  = wsf + 6ull * MTOT;          // 688128 (moments / stat partials)
    float* red64 = part + 688128;              // 64*42 = 2688
    float* c1    = red64 + 2688;               // 64
    float* c2    = c1 + 64;                    // 64
    float* A3    = c2 + 64;                    // 128
    float* c3    = A3 + 128;                   // 128
    short* wf1   = (short*)(c3 + 128);         // 2048 shorts (4 frags)
    short* wf2r  = wf1 + 2048;                 // 4096 shorts (8 frags, raw)
    short* wf2f  = wf2r + 4096;                // 4096 shorts (8 frags, folded)
    short* wf3   = wf2f + 4096;                // 8192 shorts (16 frags, raw)

    fps_kernel<<<dim3(BB), dim3(256), 0, stream>>>(xyz, newxyz);
    ball_gather_kernel<<<dim3(4096), dim3(256), 0, stream>>>(xyz, feat, newxyz, v, part);
    reduce1_kernel<<<dim3(64), dim3(256), 0, stream>>>(part, red64);
    finalize1_kernel<<<dim3(1), dim3(1024), 0, stream>>>(red64, w0, g0, bt0, w1, w2,
                                                         wf1, c1, wf2r, wf3);

    chain_kernel<2><<<dim3(2048), dim3(256), 0, stream>>>(v, wf1, c1, wf2r, nullptr,
                                                          nullptr, part, nullptr, 2);
    finalize2_kernel<<<dim3(1), dim3(1024), 0, stream>>>(part, w1, g1, bt1, wf2f, c2);

    chain_kernel<3><<<dim3(2048), dim3(256), 0, stream>>>(v, wf1, c1, wf2f, c2,
                                                          wf3, part, outF, 2);
    finalize3_kernel<<<dim3(1), dim3(1024), 0, stream>>>(part, g2, bt2, A3, c3);
    final_out_kernel<<<dim3(2048), dim3(256), 0, stream>>>(outF, A3, c3);
}

// Round 14
// 1151.599 us; speedup vs baseline: 1.0678x; 1.0678x over previous
//
#include <hip/hip_runtime.h>
#include <math.h>

// Problem constants
#define BB 16
#define NN 8192
#define SS 1024
#define GG 32
#define MTOT (BB*SS*GG)   // 524288
// MLP: 6 -> 64 -> 64 -> 128

struct alignas(16) f4 { float v[4]; };

typedef __attribute__((ext_vector_type(8))) short bfrag;   // 8 bf16 = 4 VGPR
typedef __attribute__((ext_vector_type(4))) float facc;    // 4 f32 acc

#define MFMA16(a, b, c) __builtin_amdgcn_mfma_f32_16x16x32_bf16(a, b, c, 0, 0, 0)

__device__ __forceinline__ unsigned short f2bf(float f) {
    const unsigned u = __float_as_uint(f);
    return (unsigned short)((u + 0x7FFFu + ((u >> 16) & 1u)) >> 16);
}
__device__ __forceinline__ unsigned packbf(float lo, float hi) {
    return (unsigned)f2bf(lo) | ((unsigned)f2bf(hi) << 16);
}

template<int CTRL>
__device__ __forceinline__ int dppmov(int x) {
    return __builtin_amdgcn_update_dpp(x, x, CTRL, 0xF, 0xF, true);
}
// one u64 max-reduce level via DPP permutation of (hi,lo)
template<int CTRL>
__device__ __forceinline__ void dlevel(int& hi, int& lo) {
    const int oh = dppmov<CTRL>(hi);
    const int ol = dppmov<CTRL>(lo);
    const unsigned long long o =
        ((unsigned long long)(unsigned)oh << 32) | (unsigned)ol;
    const unsigned long long c =
        ((unsigned long long)(unsigned)hi << 32) | (unsigned)lo;
    if (o > c) { hi = oh; lo = ol; }
}
// 16-lane-group sum via ROW_ROR rotate-reduce (every lane gets group total)
__device__ __forceinline__ float dppadd16(float x) {
    x += __int_as_float(dppmov<0x121>(__float_as_int(x)));   // ROW_ROR:1
    x += __int_as_float(dppmov<0x122>(__float_as_int(x)));   // ROW_ROR:2
    x += __int_as_float(dppmov<0x124>(__float_as_int(x)));   // ROW_ROR:4
    x += __int_as_float(dppmov<0x128>(__float_as_int(x)));   // ROW_ROR:8
    return x;
}

// ---------------------------------------------------------------------------
// FPS — round-10/12 reduce shape (measured 917 us; LDS-slot flattening,
// spin-flags, store-deferral+coord-fusion, and 512-thr variants ALL
// regressed — this is the empirical optimum). Scalar __f*_rn distance math
// ONLY (packed-f32 failed twice with identical wrong output — dead end).
// ---------------------------------------------------------------------------
__global__ __launch_bounds__(256) void fps_kernel(const float* __restrict__ xyz,
                                                  float* __restrict__ newxyz)
{
    __shared__ float lx[NN], ly[NN], lz[NN];            // 96 KB
    __shared__ unsigned long long slots[2][4];
    const int b = blockIdx.x;
    const int t = threadIdx.x;
    const int wave = t >> 6, lane = t & 63;
    const float* base = xyz + (size_t)b * NN * 3;

    float px[32], py[32], pz[32], dd[32];
#pragma unroll
    for (int k = 0; k < 32; ++k) {
        const int p = (k << 8) + t;
        const float x = base[p * 3 + 0];
        const float y = base[p * 3 + 1];
        const float z = base[p * 3 + 2];
        px[k] = x; py[k] = y; pz[k] = z; dd[k] = 1e10f;
        lx[p] = x; ly[p] = y; lz[p] = z;
    }
    __syncthreads();

    int far = 0;
    float* outb = newxyz + (size_t)b * SS * 3;
    for (int s = 0; s < SS; ++s) {
        const float cx = lx[far], cy = ly[far], cz = lz[far];
        if (t == 0) {
            outb[s * 3 + 0] = cx;
            outb[s * 3 + 1] = cy;
            outb[s * 3 + 2] = cz;
        }
        float bf = -1.f;
        unsigned binv = 0u;
#pragma unroll
        for (int k = 0; k < 32; ++k) {
            const float dx = __fsub_rn(px[k], cx);
            const float dy = __fsub_rn(py[k], cy);
            const float dz = __fsub_rn(pz[k], cz);
            const float d  = __fadd_rn(__fadd_rn(__fmul_rn(dx, dx), __fmul_rn(dy, dy)),
                                       __fmul_rn(dz, dz));
            const float nd = fminf(dd[k], d);
            dd[k] = nd;
            if (nd > bf) {                         // strict > keeps lowest k
                bf = nd;
                binv = 0xFFFFFFFFu - (unsigned)((k << 8) + t);
            }
        }

        int hi = __float_as_int(bf);   // bf >= 0 -> monotone bit pattern
        int lo = (int)binv;
        dlevel<0x121>(hi, lo);         // ROW_ROR:1
        dlevel<0x122>(hi, lo);         // ROW_ROR:2
        dlevel<0x124>(hi, lo);         // ROW_ROR:4
        dlevel<0x128>(hi, lo);         // ROW_ROR:8  -> max over each 16-row
        {
            const int oh = __shfl_xor(hi, 16), ol = __shfl_xor(lo, 16);
            const unsigned long long o =
                ((unsigned long long)(unsigned)oh << 32) | (unsigned)ol;
            const unsigned long long c =
                ((unsigned long long)(unsigned)hi << 32) | (unsigned)lo;
            if (o > c) { hi = oh; lo = ol; }
        }
        {
            const int oh = __shfl_xor(hi, 32), ol = __shfl_xor(lo, 32);
            const unsigned long long o =
                ((unsigned long long)(unsigned)oh << 32) | (unsigned)ol;
            const unsigned long long c =
                ((unsigned long long)(unsigned)hi << 32) | (unsigned)lo;
            if (o > c) { hi = oh; lo = ol; }
        }

        if (lane == 0)
            slots[s & 1][wave] =
                ((unsigned long long)(unsigned)hi << 32) | (unsigned)lo;
        __syncthreads();
        unsigned long long g = slots[s & 1][0];
#pragma unroll
        for (int w = 1; w < 4; ++w) {
            const unsigned long long o = slots[s & 1][w];
            g = (o > g) ? o : g;
        }
        far = (int)(0xFFFFFFFFu - (unsigned)(g & 0xFFFFFFFFull));
    }
}

// ---------------------------------------------------------------------------
// ball query + gather + v moments. 2-chunk unrolled scan: both chunks' loads
// issue back-to-back (2x memory-level parallelism vs the serial
// load->exit-check chain). Semantics identical: pos<GG guard drops overflow
// hits; cnt accounting exact; pad path unchanged.
// ---------------------------------------------------------------------------
__global__ __launch_bounds__(256) void ball_gather_kernel(const float* __restrict__ xyz,
                                                          const float* __restrict__ feat,
                                                          const float* __restrict__ newxyz,
                                                          float* __restrict__ v,
                                                          float* __restrict__ part1)
{
    const int wid  = (int)((blockIdx.x * 256 + threadIdx.x) >> 6);
    const int lane = threadIdx.x & 63;
    if (wid >= BB * SS) return;
    const int b = wid >> 10;

    const float cx = newxyz[wid * 3 + 0];
    const float cy = newxyz[wid * 3 + 1];
    const float cz = newxyz[wid * 3 + 2];
    const float* xb = xyz + (size_t)b * NN * 3;
    const float* fb = feat + (size_t)b * NN * 3;
    const size_t mbase = (size_t)wid * GG;

    float mS[6];
    float mP[36];
#pragma unroll
    for (int c = 0; c < 6; ++c) mS[c] = 0.f;
#pragma unroll
    for (int c = 0; c < 36; ++c) mP[c] = 0.f;

    int cnt = 0, firstp = -1;

    auto emit = [&](int p, float x, float y, float z, int pos) {
        const size_t mm = mbase + pos;
        float a[6];
        a[0] = __fsub_rn(x, cx);
        a[1] = __fsub_rn(y, cy);
        a[2] = __fsub_rn(z, cz);
        a[3] = fb[p * 3 + 0];
        a[4] = fb[p * 3 + 1];
        a[5] = fb[p * 3 + 2];
#pragma unroll
        for (int c = 0; c < 6; ++c) {
            v[(size_t)c * MTOT + mm] = a[c];
            mS[c] += a[c];
#pragma unroll
            for (int dch = 0; dch < 6; ++dch)
                mP[c * 6 + dch] = fmaf(a[c], a[dch], mP[c * 6 + dch]);
        }
    };

    for (int base = 0; base < NN && cnt < GG; base += 128) {
        const int pA = base + lane;
        const int pB = base + 64 + lane;
        // issue both chunks' loads up front (independent -> overlapped)
        const float xA = xb[pA * 3 + 0], yA = xb[pA * 3 + 1], zA = xb[pA * 3 + 2];
        const float xB = xb[pB * 3 + 0], yB = xb[pB * 3 + 1], zB = xb[pB * 3 + 2];

        const float dxA = __fsub_rn(cx, xA), dyA = __fsub_rn(cy, yA), dzA = __fsub_rn(cz, zA);
        const float dA  = __fadd_rn(__fadd_rn(__fmul_rn(dxA, dxA), __fmul_rn(dyA, dyA)),
                                    __fmul_rn(dzA, dzA));
        const float dxB = __fsub_rn(cx, xB), dyB = __fsub_rn(cy, yB), dzB = __fsub_rn(cz, zB);
        const float dB  = __fadd_rn(__fadd_rn(__fmul_rn(dxB, dxB), __fmul_rn(dyB, dyB)),
                                    __fmul_rn(dzB, dzB));

        const bool hitA = (dA <= 0.04f);
        const bool hitB = (dB <= 0.04f);
        const unsigned long long mA = __ballot(hitA);
        const unsigned long long mB = __ballot(hitB);

        if (firstp < 0) {
            if (mA != 0ull)      firstp = base + (int)__builtin_ctzll(mA);
            else if (mB != 0ull) firstp = base + 64 + (int)__builtin_ctzll(mB);
        }

        const int posA = cnt + (int)__popcll(mA & ((1ull << lane) - 1ull));
        if (hitA && posA < GG) emit(pA, xA, yA, zA, posA);
        const int cntA = cnt + (int)__popcll(mA);

        const int posB = cntA + (int)__popcll(mB & ((1ull << lane) - 1ull));
        if (hitB && posB < GG) emit(pB, xB, yB, zB, posB);
        cnt = cntA + (int)__popcll(mB);
    }
    if (cnt < GG) {
        const int p = firstp;
        const float x = xb[p * 3 + 0], y = xb[p * 3 + 1], z = xb[p * 3 + 2];
        float a[6];
        a[0] = __fsub_rn(x, cx);
        a[1] = __fsub_rn(y, cy);
        a[2] = __fsub_rn(z, cz);
        a[3] = fb[p * 3 + 0];
        a[4] = fb[p * 3 + 1];
        a[5] = fb[p * 3 + 2];
        for (int j = cnt + lane; j < GG; j += 64) {
            const size_t mm = mbase + j;
#pragma unroll
            for (int c = 0; c < 6; ++c) {
                v[(size_t)c * MTOT + mm] = a[c];
                mS[c] += a[c];
#pragma unroll
                for (int dch = 0; dch < 6; ++dch)
                    mP[c * 6 + dch] = fmaf(a[c], a[dch], mP[c * 6 + dch]);
            }
        }
    }
#pragma unroll
    for (int off = 1; off < 64; off <<= 1) {
#pragma unroll
        for (int c = 0; c < 6; ++c) mS[c] += __shfl_xor(mS[c], off);
#pragma unroll
        for (int c = 0; c < 36; ++c) mP[c] += __shfl_xor(mP[c], off);
    }
    if (lane == 0) {
        float* row = part1 + (size_t)wid * 42;
#pragma unroll
        for (int c = 0; c < 6; ++c) row[c] = mS[c];
#pragma unroll
        for (int c = 0; c < 36; ++c) row[6 + c] = mP[c];
    }
}

// ---------------------------------------------------------------------------
// reduce1: collapse part1 (16384 x 42) -> red64 (64 x 42). 64 blocks x 256.
// ---------------------------------------------------------------------------
__global__ __launch_bounds__(256) void reduce1_kernel(const float* __restrict__ part1,
                                                      float* __restrict__ red64)
{
    __shared__ float ldsT[42][260];
    const int tid = threadIdx.x;
    const int row = (int)blockIdx.x * 256 + tid;
    const float* rp = part1 + (size_t)row * 42;
    float r42[42];
#pragma unroll
    for (int i = 0; i < 21; ++i) {
        const float2 v2 = *reinterpret_cast<const float2*>(rp + 2 * i);
        r42[2 * i] = v2.x; r42[2 * i + 1] = v2.y;
    }
#pragma unroll
    for (int c = 0; c < 42; ++c) ldsT[c][tid] = r42[c];
    __syncthreads();
    if (tid < 168) {
        const int c = tid >> 2, r = tid & 3;
        float s = 0.f;
#pragma unroll
        for (int k = 0; k < 64; ++k) s += ldsT[c][r * 64 + k];
        ldsT[c][256 + r] = s;   // pad columns 256..259
    }
    __syncthreads();
    if (tid < 42)
        red64[(size_t)blockIdx.x * 42 + tid] =
            (ldsT[tid][256] + ldsT[tid][257]) + (ldsT[tid][258] + ldsT[tid][259]);
}

// ---------------------------------------------------------------------------
// finalize1 (+prep merged, 1024 thr): build raw bf16 W2/W3 A-frags; reduce
// red64 (64 x 42); analytic BN1; emit folded W1 frags + c1.
// ---------------------------------------------------------------------------
__global__ __launch_bounds__(1024) void finalize1_kernel(const float* __restrict__ red64,
                                                         const float* __restrict__ w0,
                                                         const float* __restrict__ g0,
                                                         const float* __restrict__ bt0,
                                                         const float* __restrict__ w1g,
                                                         const float* __restrict__ w2g,
                                                         short* __restrict__ wf1,
                                                         float* __restrict__ c1,
                                                         short* __restrict__ wf2r,
                                                         short* __restrict__ wf3r)
{
    const int tid = threadIdx.x;
    if (tid < 512) {
        const int f = tid >> 6, l = tid & 63;
        const int o = (f >> 1) * 16 + (l & 15);
        const int kb = (f & 1) * 32 + (l >> 4) * 8;
#pragma unroll
        for (int j = 0; j < 8; ++j)
            wf2r[tid * 8 + j] = (short)f2bf(w1g[o * 64 + kb + j]);
    }
    {
        const int f = tid >> 6, l = tid & 63;
        const int o = (f >> 1) * 16 + (l & 15);
        const int kb = (f & 1) * 32 + (l >> 4) * 8;
#pragma unroll
        for (int j = 0; j < 8; ++j)
            wf3r[tid * 8 + j] = (short)f2bf(w2g[o * 64 + kb + j]);
    }

    __shared__ double red[672];
    __shared__ double tot[42];
    __shared__ float Asf[64];
    if (tid < 672) {
        const int j = tid % 42, r = tid / 42;   // 16 reducers per moment
        double s = 0.0;
#pragma unroll
        for (int i = r; i < 64; i += 16) s += (double)red64[(size_t)i * 42 + j];
        red[tid] = s;
    }
    __syncthreads();
    if (tid < 42) {
        double s = 0.0;
        for (int r = 0; r < 16; ++r) s += red[r * 42 + tid];
        tot[tid] = s / (double)MTOT;
    }
    __syncthreads();
    if (tid < 64) {
        double m1 = 0.0;
        for (int c = 0; c < 6; ++c) m1 += (double)w0[tid * 6 + c] * tot[c];
        double e2 = 0.0;
        for (int c = 0; c < 6; ++c)
            for (int d = 0; d < 6; ++d)
                e2 += (double)w0[tid * 6 + c] * (double)w0[tid * 6 + d] * tot[6 + c * 6 + d];
        double var = e2 - m1 * m1;
        if (var < 0.0) var = 0.0;
        const double A = (double)g0[tid] / sqrt(var + 1e-5);
        Asf[tid] = (float)A;
        c1[tid] = (float)((double)bt0[tid] - A * m1);
    }
    __syncthreads();
    if (tid < 256) {
        const int l = tid & 63;
        const int o = (tid >> 6) * 16 + (l & 15);
        const int h = l >> 4;
#pragma unroll
        for (int j = 0; j < 8; ++j) {
            const float val = (h == 0 && j < 6) ? Asf[o] * w0[o * 6 + j] : 0.f;
            wf1[tid * 8 + j] = (short)f2bf(val);
        }
    }
}

// ---------------------------------------------------------------------------
// MFMA chain kernel (DPP rotate-add stats reduce).
// PHASE 2: stats of x2_nb. PHASE 3: stats of x3_nb + pre-BN3 group max.
// ---------------------------------------------------------------------------
template<int PHASE>
__global__ __launch_bounds__(256, 2) void chain_kernel(
    const float* __restrict__ v,
    const short* __restrict__ wf1, const float* __restrict__ c1,
    const short* __restrict__ wf2, const float* __restrict__ c2,
    const short* __restrict__ wf3,
    float* __restrict__ part, float* __restrict__ gmax, int tpb)
{
    __shared__ alignas(16) unsigned Hu1[4][16][36];
    __shared__ alignas(16) unsigned Hu2[(PHASE == 3) ? 4 : 1][16][36];
    __shared__ alignas(16) short w3l[(PHASE == 3) ? 8192 : 8];
    __shared__ alignas(16) float gm[(PHASE == 3) ? 4 : 1][128][20];
    __shared__ float redf[4][4][64];

    const int tid = threadIdx.x;
    const int w = tid >> 6, l = tid & 63;
    const int mcol = l & 15, h = l >> 4;

    if constexpr (PHASE == 3) {
        const unsigned* src = (const unsigned*)wf3;
        unsigned* dst = (unsigned*)w3l;
        for (int i = tid; i < 4096; i += 256) dst[i] = src[i];
    }
    __syncthreads();

    bfrag a1[4];
#pragma unroll
    for (int t = 0; t < 4; ++t) a1[t] = *(const bfrag*)&wf1[(t * 64 + l) * 8];
    bfrag a2[8];
#pragma unroll
    for (int f = 0; f < 8; ++f) a2[f] = *(const bfrag*)&wf2[(f * 64 + l) * 8];
    float c1v[16];
#pragma unroll
    for (int t = 0; t < 4; ++t)
#pragma unroll
        for (int r = 0; r < 4; ++r) c1v[t * 4 + r] = c1[t * 16 + h * 4 + r];
    float c2v[16];
    if constexpr (PHASE == 3) {
#pragma unroll
        for (int t = 0; t < 4; ++t)
#pragma unroll
            for (int r = 0; r < 4; ++r) c2v[t * 4 + r] = c2[t * 16 + h * 4 + r];
    }

    constexpr int NS = (PHASE == 3) ? 32 : 16;
    float sA[NS], qA[NS];
#pragma unroll
    for (int i = 0; i < NS; ++i) { sA[i] = 0.f; qA[i] = 0.f; }

    const facc zf = {0.f, 0.f, 0.f, 0.f};

    for (int ti = 0; ti < tpb; ++ti) {
        const int tile = blockIdx.x * tpb + ti;
        float mx[(PHASE == 3) ? 32 : 1];
        if constexpr (PHASE == 3) {
#pragma unroll
            for (int i = 0; i < 32; ++i) mx[i] = -3.0e38f;
        }

#pragma unroll
        for (int st = 0; st < 2; ++st) {
            const int mg = tile * 128 + w * 32 + st * 16 + mcol;

            bfrag bv;
#pragma unroll
            for (int j = 0; j < 8; ++j) bv[j] = 0;
            if (h == 0) {
#pragma unroll
                for (int j = 0; j < 6; ++j)
                    bv[j] = (short)f2bf(v[(size_t)j * MTOT + mg]);
            }
            facc x1[4];
#pragma unroll
            for (int t = 0; t < 4; ++t) x1[t] = MFMA16(a1[t], bv, zf);
#pragma unroll
            for (int t = 0; t < 4; ++t)
#pragma unroll
                for (int rr = 0; rr < 2; ++rr)
                    Hu1[w][mcol][t * 8 + h * 2 + rr] = packbf(
                        fmaxf(x1[t][2 * rr]     + c1v[t * 4 + 2 * rr],     0.f),
                        fmaxf(x1[t][2 * rr + 1] + c1v[t * 4 + 2 * rr + 1], 0.f));

            const bfrag b0 = *(const bfrag*)&Hu1[w][mcol][h * 4];
            const bfrag b1 = *(const bfrag*)&Hu1[w][mcol][16 + h * 4];

            if constexpr (PHASE == 2) {
#pragma unroll
                for (int t = 0; t < 4; ++t) {
                    facc a = MFMA16(a2[2 * t], b0, zf);
                    a = MFMA16(a2[2 * t + 1], b1, a);
#pragma unroll
                    for (int r = 0; r < 4; ++r) {
                        const float x = a[r];
                        sA[t * 4 + r] += x;
                        qA[t * 4 + r] = fmaf(x, x, qA[t * 4 + r]);
                    }
                }
            } else {
#pragma unroll
                for (int t = 0; t < 4; ++t) {
                    facc a = MFMA16(a2[2 * t], b0, zf);
                    a = MFMA16(a2[2 * t + 1], b1, a);
#pragma unroll
                    for (int rr = 0; rr < 2; ++rr)
                        Hu2[w][mcol][t * 8 + h * 2 + rr] = packbf(
                            fmaxf(a[2 * rr]     + c2v[t * 4 + 2 * rr],     0.f),
                            fmaxf(a[2 * rr + 1] + c2v[t * 4 + 2 * rr + 1], 0.f));
                }
                const bfrag d0 = *(const bfrag*)&Hu2[w][mcol][h * 4];
                const bfrag d1 = *(const bfrag*)&Hu2[w][mcol][16 + h * 4];
#pragma unroll
                for (int t3 = 0; t3 < 8; ++t3) {
                    const bfrag wa = *(const bfrag*)&w3l[((t3 * 2 + 0) * 64 + l) * 8];
                    const bfrag wb = *(const bfrag*)&w3l[((t3 * 2 + 1) * 64 + l) * 8];
                    facc a = MFMA16(wa, d0, zf);
                    a = MFMA16(wb, d1, a);
#pragma unroll
                    for (int r = 0; r < 4; ++r) {
                        const float x = a[r];
                        const int i = t3 * 4 + r;
                        sA[i] += x;
                        qA[i] = fmaf(x, x, qA[i]);
                        mx[i] = fmaxf(mx[i], x);
                    }
                }
            }
        }

        if constexpr (PHASE == 3) {
#pragma unroll
            for (int t3 = 0; t3 < 8; ++t3)
#pragma unroll
                for (int r = 0; r < 4; ++r)
                    gm[w][t3 * 16 + h * 4 + r][mcol] = mx[t3 * 4 + r];
            float m0 = -3.0e38f, m1 = -3.0e38f;
#pragma unroll
            for (int c4i = 0; c4i < 4; ++c4i) {
                const facc v0 = *(const facc*)&gm[w][2 * l][c4i * 4];
                const facc v1 = *(const facc*)&gm[w][2 * l + 1][c4i * 4];
#pragma unroll
                for (int jj = 0; jj < 4; ++jj) {
                    m0 = fmaxf(m0, v0[jj]);
                    m1 = fmaxf(m1, v1[jj]);
                }
            }
            const int g = tile * 4 + w;
            gmax[(size_t)g * 128 + 2 * l]     = m0;
            gmax[(size_t)g * 128 + 2 * l + 1] = m1;
        }
    }

    // 16-lane-group stats reduce via DPP rotate-add (VALU pipe)
#pragma unroll
    for (int i = 0; i < NS; ++i) {
        sA[i] = dppadd16(sA[i]);
        qA[i] = dppadd16(qA[i]);
    }
    __syncthreads();
    if (mcol == 0) {
#pragma unroll
        for (int i = 0; i < NS; ++i) {
            redf[w][h][i] = sA[i];
            redf[w][h][NS + i] = qA[i];
        }
    }
    __syncthreads();
    if constexpr (PHASE == 2) {
        if (tid < 128) {
            const int o = tid & 63, sq = tid >> 6;
            const int i = (o >> 4) * 4 + (o & 3), hh = (o >> 2) & 3;
            const int idx = sq * 16 + i;
            const float s = redf[0][hh][idx] + redf[1][hh][idx] +
                            redf[2][hh][idx] + redf[3][hh][idx];
            part[(size_t)blockIdx.x * 128 + sq * 64 + o] = s;
        }
    } else {
        if (tid < 256) {
            const int o = tid & 127, sq = tid >> 7;
            const int i = (o >> 4) * 4 + (o & 3), hh = (o >> 2) & 3;
            const int idx = sq * 32 + i;
            const float s = redf[0][hh][idx] + redf[1][hh][idx] +
                            redf[2][hh][idx] + redf[3][hh][idx];
            part[(size_t)blockIdx.x * 256 + sq * 128 + o] = s;
        }
    }
}

// ---------------------------------------------------------------------------
// finalize2 (1024 thr, 8 reducers/stat, unroll-4): chain<2> partials
// (2048 x [s64|q64]) -> A2/c2; emit folded bf16 W2 A-frags.
// ---------------------------------------------------------------------------
__global__ __launch_bounds__(1024) void finalize2_kernel(const float* __restrict__ part,
                                                         const float* __restrict__ w1g,
                                                         const float* __restrict__ g1,
                                                         const float* __restrict__ bt1,
                                                         short* __restrict__ wf2f,
                                                         float* __restrict__ c2)
{
    __shared__ double tot[1024];
    __shared__ float As[64];
    const int tid = threadIdx.x;
    const int j = tid & 127, r = tid >> 7;    // 8 reducers per stat
    double s = 0.0;
#pragma unroll 4
    for (int blk = r; blk < 2048; blk += 8) s += (double)part[(size_t)blk * 128 + j];
    tot[tid] = s;
    __syncthreads();
    if (tid < 128) {
        double t = 0.0;
#pragma unroll
        for (int g = 0; g < 8; ++g) t += tot[g * 128 + tid];
        tot[tid] = t;
    }
    __syncthreads();
    if (tid < 64) {
        const double mean = tot[tid] / (double)MTOT;
        double var = tot[64 + tid] / (double)MTOT - mean * mean;
        if (var < 0.0) var = 0.0;
        const double A = (double)g1[tid] / sqrt(var + 1e-5);
        As[tid] = (float)A;
        c2[tid] = (float)((double)bt1[tid] - A * mean);
    }
    __syncthreads();
    if (tid < 512) {
        const int f = tid >> 6, l = tid & 63;
        const int o = (f >> 1) * 16 + (l & 15);
        const int kb = (f & 1) * 32 + (l >> 4) * 8;
#pragma unroll
        for (int j8 = 0; j8 < 8; ++j8)
            wf2f[tid * 8 + j8] = (short)f2bf(As[o] * w1g[o * 64 + kb + j8]);
    }
}

// ---------------------------------------------------------------------------
// finalize3 (1024 thr, 4 reducers/stat, unroll-4): chain<3> partials
// (2048 x [s128|q128]) -> A3/c3.
// ---------------------------------------------------------------------------
__global__ __launch_bounds__(1024) void finalize3_kernel(const float* __restrict__ part,
                                                         const float* __restrict__ g2,
                                                         const float* __restrict__ bt2,
                                                         float* __restrict__ A3,
                                                         float* __restrict__ c3)
{
    __shared__ double tot[1024];
    const int tid = threadIdx.x;
    const int j = tid & 255, r = tid >> 8;    // 4 reducers per stat
    double s = 0.0;
#pragma unroll 4
    for (int blk = r; blk < 2048; blk += 4) s += (double)part[(size_t)blk * 256 + j];
    tot[tid] = s;
    __syncthreads();
    if (tid < 256) {
        const double t = tot[tid] + tot[256 + tid] + tot[512 + tid] + tot[768 + tid];
        tot[tid] = t;
    }
    __syncthreads();
    if (tid < 128) {
        const double mean = tot[tid] / (double)MTOT;
        double var = tot[128 + tid] / (double)MTOT - mean * mean;
        if (var < 0.0) var = 0.0;
        const double A = (double)g2[tid] / sqrt(var + 1e-5);
        A3[tid] = (float)A;
        c3[tid] = (float)((double)bt2[tid] - A * mean);
    }
}

// ---------------------------------------------------------------------------
// final_out: in-place out = relu(A3*gmax + c3) over (16384 groups x 128 ch).
// ---------------------------------------------------------------------------
__global__ __launch_bounds__(256) void final_out_kernel(float* __restrict__ outF,
                                                        const float* __restrict__ A3,
                                                        const float* __restrict__ c3)
{
    __shared__ float As[128], Cs[128];
    const int tid = threadIdx.x;
    if (tid < 128) { As[tid] = A3[tid]; Cs[tid] = c3[tid]; }
    __syncthreads();
    const int idx = (int)blockIdx.x * 256 + tid;      // f4 index, total 524288
    f4 val = *reinterpret_cast<f4*>(&outF[(size_t)idx * 4]);
    const int chb = (idx * 4) & 127;
#pragma unroll
    for (int jj = 0; jj < 4; ++jj)
        val.v[jj] = fmaxf(fmaf(As[chb + jj], val.v[jj], Cs[chb + jj]), 0.f);
    *reinterpret_cast<f4*>(&outF[(size_t)idx * 4]) = val;
}

// ---------------------------------------------------------------------------
extern "C" void kernel_launch(void* const* d_in, const int* in_sizes, int n_in,
                              void* d_out, int out_size, void* d_ws, size_t ws_size,
                              hipStream_t stream)
{
    const float* xyz  = (const float*)d_in[0];
    const float* feat = (const float*)d_in[1];
    const float* w0  = (const float*)d_in[2];
    const float* g0  = (const float*)d_in[4];
    const float* bt0 = (const float*)d_in[5];
    const float* w1  = (const float*)d_in[6];
    const float* g1  = (const float*)d_in[8];
    const float* bt1 = (const float*)d_in[9];
    const float* w2  = (const float*)d_in[10];
    const float* g2  = (const float*)d_in[12];
    const float* bt2 = (const float*)d_in[13];

    float* out    = (float*)d_out;
    float* newxyz = out;                 // (16,1024,3)
    float* outF   = out + BB * SS * 3;   // (16,1024,128) — gmax then final

    float* wsf   = (float*)d_ws;
    float* v     = wsf;                        // 3145728 floats
    float* part  = wsf + 6ull * MTOT;          // 688128 (moments / stat partials)
    float* red64 = part + 688128;              // 64*42 = 2688
    float* c1    = red64 + 2688;               // 64
    float* c2    = c1 + 64;                    // 64
    float* A3    = c2 + 64;                    // 128
    float* c3    = A3 + 128;                   // 128
    short* wf1   = (short*)(c3 + 128);         // 2048 shorts (4 frags)
    short* wf2r  = wf1 + 2048;                 // 4096 shorts (8 frags, raw)
    short* wf2f  = wf2r + 4096;                // 4096 shorts (8 frags, folded)
    short* wf3   = wf2f + 4096;                // 8192 shorts (16 frags, raw)

    fps_kernel<<<dim3(BB), dim3(256), 0, stream>>>(xyz, newxyz);
    ball_gather_kernel<<<dim3(4096), dim3(256), 0, stream>>>(xyz, feat, newxyz, v, part);
    reduce1_kernel<<<dim3(64), dim3(256), 0, stream>>>(part, red64);
    finalize1_kernel<<<dim3(1), dim3(1024), 0, stream>>>(red64, w0, g0, bt0, w1, w2,
                                                         wf1, c1, wf2r, wf3);

    chain_kernel<2><<<dim3(2048), dim3(256), 0, stream>>>(v, wf1, c1, wf2r, nullptr,
                                                          nullptr, part, nullptr, 2);
    finalize2_kernel<<<dim3(1), dim3(1024), 0, stream>>>(part, w1, g1, bt1, wf2f, c2);

    chain_kernel<3><<<dim3(2048), dim3(256), 0, stream>>>(v, wf1, c1, wf2f, c2,
                                                          wf3, part, outF, 2);
    finalize3_kernel<<<dim3(1), dim3(1024), 0, stream>>>(part, g2, bt2, A3, c3);
    final_out_kernel<<<dim3(2048), dim3(256), 0, stream>>>(outF, A3, c3);
}